// Round 11
// baseline (6151.979 us; speedup 1.0000x reference)
//
#include <hip/hip_runtime.h>

#define HDIM 128
#define TDIM 2048
#define BDIM 256
#define NT 256            // 4 waves: halves the per-step LDS convoy + barrier cost
#define CHUNK 16
#define XGP 20            // xg pitch (dwords)

typedef _Float16 half8_t __attribute__((ext_vector_type(8)));
typedef float f32x4 __attribute__((ext_vector_type(4)));

__device__ __forceinline__ f32x4 mfma16(half8_t a, half8_t b, f32x4 c) {
    return __builtin_amdgcn_mfma_f32_16x16x32_f16(a, b, c, 0, 0, 0);
}
// MFMA with B pinned in AGPRs (R10-proven: blocks rematerialization/spill).
__device__ __forceinline__ void mfma_agpr(f32x4 &d, half8_t a, half8_t b) {
    asm("v_mfma_f32_16x16x32_f16 %0, %1, %2, %0" : "+v"(d) : "v"(a), "a"(b));
}
__device__ __forceinline__ void pin_agpr(half8_t &v) { asm("" : "+a"(v)); }

__device__ __forceinline__ void fast_barrier() {
    asm volatile("s_waitcnt lgkmcnt(0)\n\ts_barrier" ::: "memory");
}

__device__ __forceinline__ float sigm_f(float x) { return 1.0f / (1.0f + __expf(-x)); }
__device__ __forceinline__ float tanh_f(float x) { return 1.0f - 2.0f / (1.0f + __expf(2.0f * x)); }

// One-time fp32 -> fp16 weight conversion. Segments of 65536: [Whh0,Wih1,Whh1,Wih2,Whh2]
__global__ __launch_bounds__(256)
void convert_w(const float* __restrict__ Whh0, const float* __restrict__ Wih1,
               const float* __restrict__ Whh1, const float* __restrict__ Wih2,
               const float* __restrict__ Whh2, _Float16* __restrict__ dst) {
    int i = blockIdx.x * 256 + threadIdx.x;
    int seg = i >> 16, off = i & 65535;
    const float* s = (seg == 0) ? Whh0 : (seg == 1) ? Wih1 : (seg == 2) ? Whh1
                   : (seg == 3) ? Wih2 : Whh2;
    dst[i] = (_Float16)s[off];
}

__global__ __launch_bounds__(NT, 1)
void lstm3_kernel(const float* __restrict__ x,   const float* __restrict__ Wih0,
                  const float* __restrict__ bih0, const float* __restrict__ bhh0,
                  const float* __restrict__ bih1, const float* __restrict__ bhh1,
                  const float* __restrict__ bih2, const float* __restrict__ bhh2,
                  const float* __restrict__ fc1w, const float* __restrict__ fc1b,
                  const float* __restrict__ fc2w, const float* __restrict__ fc2b,
                  float* __restrict__ out,
                  _Float16* __restrict__ gbuf, const _Float16* __restrict__ wbuf)
{
    __shared__ __align__(16) _Float16 hwin_s[CHUNK][HDIM];    // rolling h window
    __shared__ __align__(16) _Float16 xin_s[2][CHUNK][HDIM];  // staged input chunks
    __shared__ __align__(16) float xg_s[2][512 * XGP];        // input projections
    __shared__ __align__(16) float z_s[64];

    const int tid = threadIdx.x, ln = tid & 63, wv = tid >> 6;  // wv in 0..3
    const int n16 = ln & 15, qd = ln >> 4, kb = qd * 8;
    const int un0 = wv * 32 + n16, un1 = un0 + 16;              // this lane's 2 units
    const int b = blockIdx.x;

    const _Float16* whhL[3] = {wbuf, wbuf + 2 * 65536, wbuf + 4 * 65536};
    const _Float16* wihL[3] = {nullptr, wbuf + 1 * 65536, wbuf + 3 * 65536};
    const float* bihL[3] = {bih0, bih1, bih2};
    const float* bhhL[3] = {bhh0, bhh1, bhh2};

    half8_t whh[2][4][4];   // rec B-frags for 2 unit-groups x 4 gates (AGPR-pinned)

#pragma unroll 1
    for (int layer = 0; layer < 3; ++layer) {
        float bsum[2][4], w0[2][4];
#pragma unroll
        for (int ug = 0; ug < 2; ++ug) {
            const int un = (ug == 0) ? un0 : un1;
#pragma unroll
            for (int q = 0; q < 4; ++q) {
                const int row = q * HDIM + un;
                bsum[ug][q] = bihL[layer][row] + bhhL[layer][row];
                w0[ug][q] = (layer == 0) ? Wih0[row] : 0.f;
#pragma unroll
                for (int kk = 0; kk < 4; ++kk) {
                    whh[ug][q][kk] =
                        *(const half8_t*)(whhL[layer] + (size_t)row * HDIM + kk * 32 + kb);
                    pin_agpr(whh[ug][q][kk]);
                }
            }
        }

        __syncthreads();   // real barrier: drains prev layer's gbuf stores (vmcnt)
        if (tid < HDIM) hwin_s[CHUNK - 1][tid] = (_Float16)0.f;   // h(-1)=0
        float c0 = 0.f, c1 = 0.f;

        float4 xp[4];          // layer-0 x prefetch
        int4 stage = {0, 0, 0, 0};
        if (layer == 0) {
            const float4* xq = (const float4*)(x + (size_t)b * TDIM);
#pragma unroll
            for (int i = 0; i < 4; ++i) xp[i] = xq[i];
            __syncthreads();
        } else {
            // prologue: chunk 0 -> xin_s[0]; proj -> xg_s[0]; prefetch chunk 1
            stage = ((const int4*)(gbuf + (size_t)b * TDIM * HDIM))[tid];
            ((int4*)&xin_s[0][0][0])[tid] = stage;
            __syncthreads();
            half8_t X0 = *(const half8_t*)&xin_s[0][n16][kb];
            half8_t X1 = *(const half8_t*)&xin_s[0][n16][32 + kb];
            half8_t X2 = *(const half8_t*)&xin_s[0][n16][64 + kb];
            half8_t X3 = *(const half8_t*)&xin_s[0][n16][96 + kb];
#pragma unroll 1
            for (int j = 0; j < 8; ++j) {
                const int gp = (8 * wv + j) * 16 + n16;
                const _Float16* wr = wihL[layer] + (size_t)gp * HDIM + kb;
                half8_t w0f = *(const half8_t*)(wr);
                half8_t w1f = *(const half8_t*)(wr + 32);
                half8_t w2f = *(const half8_t*)(wr + 64);
                half8_t w3f = *(const half8_t*)(wr + 96);
                f32x4 a = {0.f, 0.f, 0.f, 0.f};
                a = mfma16(X0, w0f, a);
                a = mfma16(X1, w1f, a);
                a = mfma16(X2, w2f, a);
                a = mfma16(X3, w3f, a);
                *(f32x4*)&xg_s[0][gp * XGP + qd * 4] = a;
            }
            stage = ((const int4*)(gbuf + ((size_t)b * TDIM + CHUNK) * HDIM))[tid];
        }

#pragma unroll 1
        for (int t0 = 0; t0 < TDIM; t0 += CHUNK) {
            const int ci = t0 >> 4, rbuf = ci & 1, cb = rbuf ^ 1;
            float xv[CHUNK];
            if (layer == 0) {
#pragma unroll
                for (int i = 0; i < 4; ++i) {
                    xv[4 * i] = xp[i].x; xv[4 * i + 1] = xp[i].y;
                    xv[4 * i + 2] = xp[i].z; xv[4 * i + 3] = xp[i].w;
                }
                int tn = (t0 + CHUNK < TDIM) ? (t0 + CHUNK) : t0;
                const float4* xq = (const float4*)(x + (size_t)b * TDIM + tn);
#pragma unroll
                for (int i = 0; i < 4; ++i) xp[i] = xq[i];
            } else {
                ((int4*)&xin_s[cb][0][0])[tid] = stage;
                int tn = (t0 + 2 * CHUNK < TDIM) ? (t0 + 2 * CHUNK) : t0;
                stage = ((const int4*)(gbuf + ((size_t)b * TDIM + tn) * HDIM))[tid];
            }

            float2 xgv[2][4];
#pragma unroll
            for (int tt = 0; tt < CHUNK; ++tt) {
                fast_barrier();
                const int t = t0 + tt, row = (t + CHUNK - 1) & 15;
                half8_t A0 = *(const half8_t*)&hwin_s[row][kb];
                half8_t A1 = *(const half8_t*)&hwin_s[row][32 + kb];
                half8_t A2 = *(const half8_t*)&hwin_s[row][64 + kb];
                half8_t A3 = *(const half8_t*)&hwin_s[row][96 + kb];

                // proj GEMM for chunk ci+1 (streamed B from L2; xg stored immediately)
                if (layer > 0 && tt == 0) {
                    half8_t X0 = *(const half8_t*)&xin_s[cb][n16][kb];
                    half8_t X1 = *(const half8_t*)&xin_s[cb][n16][32 + kb];
                    half8_t X2 = *(const half8_t*)&xin_s[cb][n16][64 + kb];
                    half8_t X3 = *(const half8_t*)&xin_s[cb][n16][96 + kb];
#pragma unroll 1
                    for (int j = 0; j < 8; ++j) {
                        const int gp = (8 * wv + j) * 16 + n16;
                        const _Float16* wr = wihL[layer] + (size_t)gp * HDIM + kb;
                        half8_t w0f = *(const half8_t*)(wr);
                        half8_t w1f = *(const half8_t*)(wr + 32);
                        half8_t w2f = *(const half8_t*)(wr + 64);
                        half8_t w3f = *(const half8_t*)(wr + 96);
                        f32x4 a = {0.f, 0.f, 0.f, 0.f};
                        a = mfma16(X0, w0f, a);
                        a = mfma16(X1, w1f, a);
                        a = mfma16(X2, w2f, a);
                        a = mfma16(X3, w3f, a);
                        *(f32x4*)&xg_s[cb][gp * XGP + qd * 4] = a;
                    }
                }
                if (layer > 0 && (tt & 1) == 0) {
#pragma unroll
                    for (int ug = 0; ug < 2; ++ug)
#pragma unroll
                        for (int q = 0; q < 4; ++q)
                            xgv[ug][q] = *(const float2*)
                                &xg_s[rbuf][(q * HDIM + ((ug == 0) ? un0 : un1)) * XGP + tt];
                }

                // recurrent MFMA: A-broadcast h(t-1), B resident in AGPRs
                f32x4 d[2][4];
#pragma unroll
                for (int ug = 0; ug < 2; ++ug)
#pragma unroll
                    for (int q = 0; q < 4; ++q) {
                        d[ug][q] = (f32x4){0.f, 0.f, 0.f, 0.f};
                        mfma_agpr(d[ug][q], A0, whh[ug][q][0]);
                        mfma_agpr(d[ug][q], A1, whh[ug][q][1]);
                        mfma_agpr(d[ug][q], A2, whh[ug][q][2]);
                        mfma_agpr(d[ug][q], A3, whh[ug][q][3]);
                    }
                // hazard fence with explicit deps: reads cannot hoist above the nops
                asm volatile("s_nop 7\n\ts_nop 7"
                             : "+v"(d[0][0]), "+v"(d[0][1]), "+v"(d[0][2]), "+v"(d[0][3]),
                               "+v"(d[1][0]), "+v"(d[1][1]), "+v"(d[1][2]), "+v"(d[1][3]));

#pragma unroll
                for (int ug = 0; ug < 2; ++ug) {
                    float xq[4];
                    if (layer == 0) {
#pragma unroll
                        for (int q = 0; q < 4; ++q) xq[q] = xv[tt] * w0[ug][q];
                    } else {
#pragma unroll
                        for (int q = 0; q < 4; ++q)
                            xq[q] = (tt & 1) ? xgv[ug][q].y : xgv[ug][q].x;
                    }
                    float ig = sigm_f(d[ug][0][0] + xq[0] + bsum[ug][0]);
                    float fg = sigm_f(d[ug][1][0] + xq[1] + bsum[ug][1]);
                    float gg = tanh_f(d[ug][2][0] + xq[2] + bsum[ug][2]);
                    float og = sigm_f(d[ug][3][0] + xq[3] + bsum[ug][3]);
                    float& cc = (ug == 0) ? c0 : c1;
                    cc = fg * cc + ig * gg;
                    if (qd == 0)
                        hwin_s[t & 15][(ug == 0) ? un0 : un1] = (_Float16)(og * tanh_f(cc));
                }
            }

            // flush completed chunk to gbuf (layers 0,1)
            if (layer < 2) {
                fast_barrier();
                int4 v = ((const int4*)&hwin_s[0][0])[tid];
                ((int4*)(gbuf + ((size_t)b * TDIM + t0) * HDIM))[tid] = v;
            }
        }
    }

    // ---- FC head: final h (t=2047) is hwin_s[15] ----
    __syncthreads();
    if (tid < 64) {
        const float* w = fc1w + tid * HDIM;
        float sacc = fc1b[tid];
#pragma unroll
        for (int k = 0; k < HDIM; ++k) sacc += w[k] * (float)hwin_s[CHUNK - 1][k];
        z_s[tid] = fmaxf(sacc, 0.0f);
    }
    __syncthreads();
    if (tid < 5) {
        const float* w = fc2w + tid * 64;
        float sacc = fc2b[tid];
#pragma unroll
        for (int k = 0; k < 64; ++k) sacc += w[k] * z_s[k];
        out[b * 5 + tid] = sacc;
    }
}

extern "C" void kernel_launch(void* const* d_in, const int* in_sizes, int n_in,
                              void* d_out, int out_size, void* d_ws, size_t ws_size,
                              hipStream_t stream) {
    (void)in_sizes; (void)n_in; (void)out_size; (void)ws_size;
    const float* x    = (const float*)d_in[0];
    const float* Wih0 = (const float*)d_in[1];
    const float* Whh0 = (const float*)d_in[2];
    const float* bih0 = (const float*)d_in[3];
    const float* bhh0 = (const float*)d_in[4];
    const float* Wih1 = (const float*)d_in[5];
    const float* Whh1 = (const float*)d_in[6];
    const float* bih1 = (const float*)d_in[7];
    const float* bhh1 = (const float*)d_in[8];
    const float* Wih2 = (const float*)d_in[9];
    const float* Whh2 = (const float*)d_in[10];
    const float* bih2 = (const float*)d_in[11];
    const float* bhh2 = (const float*)d_in[12];
    const float* fc1w = (const float*)d_in[13];
    const float* fc1b = (const float*)d_in[14];
    const float* fc2w = (const float*)d_in[15];
    const float* fc2b = (const float*)d_in[16];
    float* out = (float*)d_out;

    _Float16* gbuf = (_Float16*)d_ws;                 // 128 MB inter-layer buffer
    _Float16* wbuf = gbuf + (size_t)67108864;         // fp16 weights (640 KB)

    hipLaunchKernelGGL(convert_w, dim3(1280), dim3(256), 0, stream,
                       Whh0, Wih1, Whh1, Wih2, Whh2, wbuf);
    hipLaunchKernelGGL(lstm3_kernel, dim3(BDIM), dim3(NT), 0, stream,
                       x, Wih0, bih0, bhh0, bih1, bhh1, bih2, bhh2,
                       fc1w, fc1b, fc2w, fc2b, out, gbuf, wbuf);
}

// Round 12
// 3901.146 us; speedup vs baseline: 1.5770x; 1.5770x over previous
//
#include <hip/hip_runtime.h>

#define HDIM 128
#define TDIM 2048
#define BDIM 256
#define CHUNK 16
#define NT 512
#define XGP 20   // fp32 dword pitch per gate row in xg_s

typedef _Float16 half8_t __attribute__((ext_vector_type(8)));
typedef float f32x4 __attribute__((ext_vector_type(4)));

__device__ __forceinline__ f32x4 mfma16(half8_t a, half8_t b, f32x4 c) {
    return __builtin_amdgcn_mfma_f32_16x16x32_f16(a, b, c, 0, 0, 0);
}
// MFMA with B pinned in AGPRs (R10/R11-proven: blocks remat/spill of weights).
__device__ __forceinline__ void mfma_agpr(f32x4 &d, half8_t a, half8_t b) {
    asm("v_mfma_f32_16x16x32_f16 %0, %1, %2, %0" : "+v"(d) : "v"(a), "a"(b));
}
__device__ __forceinline__ void pin_agpr(half8_t &v) { asm("" : "+a"(v)); }

// Workgroup barrier WITHOUT the compiler's vmcnt(0) drain: LDS visibility only.
__device__ __forceinline__ void fast_barrier() {
    asm volatile("s_waitcnt lgkmcnt(0)\n\ts_barrier" ::: "memory");
}

__device__ __forceinline__ float sigm_f(float x) { return 1.0f / (1.0f + __expf(-x)); }
__device__ __forceinline__ float tanh_f(float x) { return 1.0f - 2.0f / (1.0f + __expf(2.0f * x)); }

// One-time fp32 -> fp16 weight conversion. Segments of 65536: [Whh0,Wih1,Whh1,Wih2,Whh2]
__global__ __launch_bounds__(256)
void convert_w(const float* __restrict__ Whh0, const float* __restrict__ Wih1,
               const float* __restrict__ Whh1, const float* __restrict__ Wih2,
               const float* __restrict__ Whh2, _Float16* __restrict__ dst) {
    int i = blockIdx.x * 256 + threadIdx.x;
    int seg = i >> 16, off = i & 65535;
    const float* s = (seg == 0) ? Whh0 : (seg == 1) ? Wih1 : (seg == 2) ? Whh1
                   : (seg == 3) ? Wih2 : Whh2;
    dst[i] = (_Float16)s[off];
}

__global__ __launch_bounds__(NT, 2)
void lstm3_kernel(const float* __restrict__ x,   const float* __restrict__ Wih0,
                  const float* __restrict__ bih0, const float* __restrict__ bhh0,
                  const float* __restrict__ bih1, const float* __restrict__ bhh1,
                  const float* __restrict__ bih2, const float* __restrict__ bhh2,
                  const float* __restrict__ fc1w, const float* __restrict__ fc1b,
                  const float* __restrict__ fc2w, const float* __restrict__ fc2b,
                  float* __restrict__ out,
                  _Float16* __restrict__ gbuf, const _Float16* __restrict__ wbuf)
{
    __shared__ __align__(16) _Float16 hwin_s[CHUNK][HDIM];    // rolling h window
    __shared__ __align__(16) _Float16 xin_s[2][CHUNK][HDIM];  // staged input chunks
    __shared__ __align__(16) float xg_s[2][512 * XGP];        // input projections
    __shared__ __align__(16) float z_s[64];

    const int tid = threadIdx.x;
    const int ln = tid & 63;
    const int wv = tid >> 6;          // wave id 0..7 -> owns units [16wv,16wv+16)
    const int n16 = ln & 15;          // unit-within-wave / MFMA column
    const int qd = ln >> 4;
    const int kb = qd * 8;            // k-element offset within a 32-block
    const int un = wv * 16 + n16;     // this lane's hidden unit
    const int b = blockIdx.x;

    // ================= layer 0 (in_dim = 1) =================
    {
        float bsum[4], w0[4];
        half8_t bhh[4][4];            // rec B-frags (AGPR-pinned)
#pragma unroll
        for (int tau = 0; tau < 4; ++tau) {
            const int g = tau * HDIM + un;
            bsum[tau] = bih0[g] + bhh0[g];
            w0[tau] = Wih0[g];
#pragma unroll
            for (int kk = 0; kk < 4; ++kk) {
                bhh[tau][kk] = *(const half8_t*)(wbuf + (size_t)g * HDIM + kk * 32 + kb);
                pin_agpr(bhh[tau][kk]);
            }
        }
        if (tid < HDIM) hwin_s[CHUNK - 1][tid] = (_Float16)0.f;
        float c = 0.f;
        float4 xp[4];
        {
            const float4* xq = (const float4*)(x + (size_t)b * TDIM);
#pragma unroll
            for (int i = 0; i < 4; ++i) xp[i] = xq[i];
        }

#pragma unroll 1
        for (int t0 = 0; t0 < TDIM; t0 += CHUNK) {
            float xv[CHUNK];
#pragma unroll
            for (int i = 0; i < 4; ++i) {
                xv[4 * i] = xp[i].x; xv[4 * i + 1] = xp[i].y;
                xv[4 * i + 2] = xp[i].z; xv[4 * i + 3] = xp[i].w;
            }
            int tn = (t0 + CHUNK < TDIM) ? (t0 + CHUNK) : t0;
            const float4* xq = (const float4*)(x + (size_t)b * TDIM + tn);
#pragma unroll
            for (int i = 0; i < 4; ++i) xp[i] = xq[i];

#pragma unroll
            for (int tt = 0; tt < CHUNK; ++tt) {
                fast_barrier();
                const int t = t0 + tt, row = (t + CHUNK - 1) & 15;
                half8_t A0 = *(const half8_t*)&hwin_s[row][kb];
                half8_t A1 = *(const half8_t*)&hwin_s[row][32 + kb];
                half8_t A2 = *(const half8_t*)&hwin_s[row][64 + kb];
                half8_t A3 = *(const half8_t*)&hwin_s[row][96 + kb];
                f32x4 d0 = {0,0,0,0}, d1 = {0,0,0,0}, d2 = {0,0,0,0}, d3 = {0,0,0,0};
                mfma_agpr(d0, A0, bhh[0][0]); mfma_agpr(d0, A1, bhh[0][1]);
                mfma_agpr(d0, A2, bhh[0][2]); mfma_agpr(d0, A3, bhh[0][3]);
                mfma_agpr(d1, A0, bhh[1][0]); mfma_agpr(d1, A1, bhh[1][1]);
                mfma_agpr(d1, A2, bhh[1][2]); mfma_agpr(d1, A3, bhh[1][3]);
                mfma_agpr(d2, A0, bhh[2][0]); mfma_agpr(d2, A1, bhh[2][1]);
                mfma_agpr(d2, A2, bhh[2][2]); mfma_agpr(d2, A3, bhh[2][3]);
                mfma_agpr(d3, A0, bhh[3][0]); mfma_agpr(d3, A1, bhh[3][1]);
                mfma_agpr(d3, A2, bhh[3][2]); mfma_agpr(d3, A3, bhh[3][3]);
                asm volatile("s_nop 7\n\ts_nop 7"
                             : "+v"(d0), "+v"(d1), "+v"(d2), "+v"(d3));
                float ig = sigm_f(d0[0] + xv[tt] * w0[0] + bsum[0]);
                float fg = sigm_f(d1[0] + xv[tt] * w0[1] + bsum[1]);
                float gg = tanh_f(d2[0] + xv[tt] * w0[2] + bsum[2]);
                float og = sigm_f(d3[0] + xv[tt] * w0[3] + bsum[3]);
                c = fg * c + ig * gg;
                if (qd == 0) hwin_s[t & 15][un] = (_Float16)(og * tanh_f(c));
            }
            fast_barrier();
            int2 v = ((const int2*)&hwin_s[0][0])[tid];
            ((int2*)(gbuf + ((size_t)b * TDIM + t0) * HDIM))[tid] = v;
        }
    }

    // ================= layers 1,2 (MFMA rec + spread MFMA proj) =================
#pragma unroll 1
    for (int layer = 1; layer < 3; ++layer) {
        const _Float16* whh_p = wbuf + (size_t)((layer == 1) ? 2 : 4) * 65536;
        const _Float16* wih_p = wbuf + (size_t)((layer == 1) ? 1 : 3) * 65536;
        const float* bih = (layer == 1) ? bih1 : bih2;
        const float* bhh = (layer == 1) ? bhh1 : bhh2;

        float bsum[4];
        half8_t bhhf[4][4];           // rec B-frags (AGPR-pinned)
#pragma unroll
        for (int tau = 0; tau < 4; ++tau) {
            const int g = tau * HDIM + un;
            bsum[tau] = bih[g] + bhh[g];
#pragma unroll
            for (int kk = 0; kk < 4; ++kk) {
                bhhf[tau][kk] = *(const half8_t*)(whh_p + (size_t)g * HDIM + kk * 32 + kb);
                pin_agpr(bhhf[tau][kk]);
            }
        }

        __syncthreads();   // REAL barrier: drains prev layer's gbuf stores before reads
        if (tid < HDIM) hwin_s[CHUNK - 1][tid] = (_Float16)0.f;
        float c = 0.f;

        // ---- prologue: proj chunk 0 -> xg_s[0] (aligned tiles), prefetch chunk 1 ----
        int2 stage = ((const int2*)(gbuf + (size_t)b * TDIM * HDIM))[tid];
        ((int2*)&xin_s[0][0][0])[tid] = stage;
        __syncthreads();
        {
            half8_t X0 = *(const half8_t*)&xin_s[0][n16][kb];
            half8_t X1 = *(const half8_t*)&xin_s[0][n16][32 + kb];
            half8_t X2 = *(const half8_t*)&xin_s[0][n16][64 + kb];
            half8_t X3 = *(const half8_t*)&xin_s[0][n16][96 + kb];
#pragma unroll
            for (int q = 0; q < 4; ++q) {
                const int g = q * HDIM + un;     // this wave's own units' gate rows
                const _Float16* wr = wih_p + (size_t)g * HDIM + kb;
                f32x4 a = {0.f, 0.f, 0.f, 0.f};
                a = mfma16(X0, *(const half8_t*)(wr),      a);
                a = mfma16(X1, *(const half8_t*)(wr + 32), a);
                a = mfma16(X2, *(const half8_t*)(wr + 64), a);
                a = mfma16(X3, *(const half8_t*)(wr + 96), a);
                *(f32x4*)&xg_s[0][g * XGP + qd * 4] = a;
            }
        }
        stage = ((const int2*)(gbuf + ((size_t)b * TDIM + CHUNK) * HDIM))[tid];

#pragma unroll 1
        for (int t0 = 0; t0 < TDIM; t0 += CHUNK) {
            const int ci = t0 >> 4, rbuf = ci & 1, cb = rbuf ^ 1;
            ((int2*)&xin_s[cb][0][0])[tid] = stage;
            int tn = (t0 + 2 * CHUNK < TDIM) ? (t0 + 2 * CHUNK) : t0;
            stage = ((const int2*)(gbuf + ((size_t)b * TDIM + tn) * HDIM))[tid];

            half8_t XF0, XF1, XF2, XF3;   // next chunk's A-frags, held over tt=0..3
            f32x4 xgq[4];                 // this chunk's xg, refreshed every 4 steps
#pragma unroll
            for (int tt = 0; tt < CHUNK; ++tt) {
                fast_barrier();
                const int t = t0 + tt, row = (t + CHUNK - 1) & 15;
                half8_t A0 = *(const half8_t*)&hwin_s[row][kb];
                half8_t A1 = *(const half8_t*)&hwin_s[row][32 + kb];
                half8_t A2 = *(const half8_t*)&hwin_s[row][64 + kb];
                half8_t A3 = *(const half8_t*)&hwin_s[row][96 + kb];

                if (tt == 0) {
                    XF0 = *(const half8_t*)&xin_s[cb][n16][kb];
                    XF1 = *(const half8_t*)&xin_s[cb][n16][32 + kb];
                    XF2 = *(const half8_t*)&xin_s[cb][n16][64 + kb];
                    XF3 = *(const half8_t*)&xin_s[cb][n16][96 + kb];
                }
                // spread proj: one gate-tile per step over tt=0..3 (own units)
                if (tt < 4) {
                    const int g = tt * HDIM + un;
                    const _Float16* wr = wih_p + (size_t)g * HDIM + kb;
                    f32x4 a = {0.f, 0.f, 0.f, 0.f};
                    a = mfma16(XF0, *(const half8_t*)(wr),      a);
                    a = mfma16(XF1, *(const half8_t*)(wr + 32), a);
                    a = mfma16(XF2, *(const half8_t*)(wr + 64), a);
                    a = mfma16(XF3, *(const half8_t*)(wr + 96), a);
                    *(f32x4*)&xg_s[cb][g * XGP + qd * 4] = a;
                }
                if ((tt & 3) == 0) {
#pragma unroll
                    for (int q = 0; q < 4; ++q)
                        xgq[q] = *(const f32x4*)&xg_s[rbuf][(q * HDIM + un) * XGP + tt];
                }

                f32x4 d0 = {0,0,0,0}, d1 = {0,0,0,0}, d2 = {0,0,0,0}, d3 = {0,0,0,0};
                mfma_agpr(d0, A0, bhhf[0][0]); mfma_agpr(d0, A1, bhhf[0][1]);
                mfma_agpr(d0, A2, bhhf[0][2]); mfma_agpr(d0, A3, bhhf[0][3]);
                mfma_agpr(d1, A0, bhhf[1][0]); mfma_agpr(d1, A1, bhhf[1][1]);
                mfma_agpr(d1, A2, bhhf[1][2]); mfma_agpr(d1, A3, bhhf[1][3]);
                mfma_agpr(d2, A0, bhhf[2][0]); mfma_agpr(d2, A1, bhhf[2][1]);
                mfma_agpr(d2, A2, bhhf[2][2]); mfma_agpr(d2, A3, bhhf[2][3]);
                mfma_agpr(d3, A0, bhhf[3][0]); mfma_agpr(d3, A1, bhhf[3][1]);
                mfma_agpr(d3, A2, bhhf[3][2]); mfma_agpr(d3, A3, bhhf[3][3]);
                asm volatile("s_nop 7\n\ts_nop 7"
                             : "+v"(d0), "+v"(d1), "+v"(d2), "+v"(d3));

                const int sel = tt & 3;
                float ig = sigm_f(d0[0] + xgq[0][sel] + bsum[0]);
                float fg = sigm_f(d1[0] + xgq[1][sel] + bsum[1]);
                float gg = tanh_f(d2[0] + xgq[2][sel] + bsum[2]);
                float og = sigm_f(d3[0] + xgq[3][sel] + bsum[3]);
                c = fg * c + ig * gg;
                if (qd == 0) hwin_s[t & 15][un] = (_Float16)(og * tanh_f(c));
            }
            if (layer == 1) {
                fast_barrier();
                int2 v = ((const int2*)&hwin_s[0][0])[tid];
                ((int2*)(gbuf + ((size_t)b * TDIM + t0) * HDIM))[tid] = v;
            }
        }
    }

    // ---- FC head: final h (t=2047) is hwin_s[15] ----
    __syncthreads();
    if (tid < 64) {
        const float* w = fc1w + tid * HDIM;
        float sacc = fc1b[tid];
#pragma unroll
        for (int k = 0; k < HDIM; ++k) sacc += w[k] * (float)hwin_s[CHUNK - 1][k];
        z_s[tid] = fmaxf(sacc, 0.0f);
    }
    __syncthreads();
    if (tid < 5) {
        const float* w = fc2w + tid * 64;
        float sacc = fc2b[tid];
#pragma unroll
        for (int k = 0; k < 64; ++k) sacc += w[k] * z_s[k];
        out[b * 5 + tid] = sacc;
    }
}

extern "C" void kernel_launch(void* const* d_in, const int* in_sizes, int n_in,
                              void* d_out, int out_size, void* d_ws, size_t ws_size,
                              hipStream_t stream) {
    (void)in_sizes; (void)n_in; (void)out_size; (void)ws_size;
    const float* x    = (const float*)d_in[0];
    const float* Wih0 = (const float*)d_in[1];
    const float* Whh0 = (const float*)d_in[2];
    const float* bih0 = (const float*)d_in[3];
    const float* bhh0 = (const float*)d_in[4];
    const float* Wih1 = (const float*)d_in[5];
    const float* Whh1 = (const float*)d_in[6];
    const float* bih1 = (const float*)d_in[7];
    const float* bhh1 = (const float*)d_in[8];
    const float* Wih2 = (const float*)d_in[9];
    const float* Whh2 = (const float*)d_in[10];
    const float* bih2 = (const float*)d_in[11];
    const float* bhh2 = (const float*)d_in[12];
    const float* fc1w = (const float*)d_in[13];
    const float* fc1b = (const float*)d_in[14];
    const float* fc2w = (const float*)d_in[15];
    const float* fc2b = (const float*)d_in[16];
    float* out = (float*)d_out;

    _Float16* gbuf = (_Float16*)d_ws;                 // 128 MB inter-layer buffer
    _Float16* wbuf = gbuf + (size_t)67108864;         // fp16 weights (640 KB)

    hipLaunchKernelGGL(convert_w, dim3(1280), dim3(256), 0, stream,
                       Whh0, Wih1, Whh1, Wih2, Whh2, wbuf);
    hipLaunchKernelGGL(lstm3_kernel, dim3(BDIM), dim3(NT), 0, stream,
                       x, Wih0, bih0, bhh0, bih1, bhh1, bih2, bhh2,
                       fc1w, fc1b, fc2w, fc2b, out, gbuf, wbuf);
}